// Round 1
// baseline (2186.139 us; speedup 1.0000x reference)
//
#include <hip/hip_runtime.h>
#include <hip/hip_bf16.h>

#define N_MET 20000
#define N_RXN 50000
#define NEDGE 1000000
#define D 128
#define DH 64

// ---- monotone float<->uint key for atomicMax on floats ----
__device__ __forceinline__ unsigned fkey(float x){
    unsigned u = __float_as_uint(x);
    return (u & 0x80000000u) ? ~u : (u | 0x80000000u);
}
__device__ __forceinline__ float fkey_inv(unsigned k){
    unsigned u = (k & 0x80000000u) ? (k ^ 0x80000000u) : ~k;
    return __uint_as_float(u);
}

// Detect whether hyperedge_index is stored as int64 (little-endian: odd 32-bit
// words are the high halves, all zero for indices < 2^31) or int32.
__global__ void detect_kernel(const unsigned* __restrict__ he, int* __restrict__ flag){
    if (threadIdx.x == 0){
        int is64 = 1;
        for (int i = 0; i < 64; ++i){
            if (he[2*i + 1] != 0u){ is64 = 0; break; }
        }
        *flag = is64;
    }
}

// Kernel 1: gate[e] = W2 . relu(W1^T f + b1) + b2 ; atomicMax per-rxn gate max.
// One block = 64 edges, 256 threads, register tile 4 edges x 4 cols.
__global__ __launch_bounds__(256) void gate_kernel(
    const float* __restrict__ feats, const int* __restrict__ he,
    const float* __restrict__ W1, const float* __restrict__ b1,
    const float* __restrict__ W2, const float* __restrict__ b2,
    float* __restrict__ gate, unsigned* __restrict__ gmaxkey,
    const int* __restrict__ flag)
{
    __shared__ float Fs[64*132];     // padded stride 132 (bank rotation)
    __shared__ float W1s[D*DH];      // [k][j] row-major
    __shared__ int   mets[64];
    __shared__ int   rxns[64];

    const int tid  = threadIdx.x;
    const int tile = blockIdx.x;
    const int stride = (*flag) ? 2 : 1;

    if (tid < 64){
        int e = tile*64 + tid;
        mets[tid] = he[(size_t)e * stride];
        rxns[tid] = he[(size_t)(NEDGE + e) * stride];
    }
    for (int i = tid; i < D*DH/4; i += 256){
        ((float4*)W1s)[i] = ((const float4*)W1)[i];
    }
    __syncthreads();

    // gather F tile: 64 rows x 128 floats, each thread 8 float4s
    {
        int er = tid >> 2;       // 0..63
        int c0 = tid & 3;
        const float4* src = (const float4*)(feats + (size_t)mets[er] * D);
        #pragma unroll
        for (int it = 0; it < 8; ++it){
            int c = c0 + 4*it;   // 0..31
            float4 v = src[c];
            *(float4*)&Fs[er*132 + c*4] = v;
        }
    }
    __syncthreads();

    const int jq = tid & 15;     // 16 col-quads
    const int eq = tid >> 4;     // 16 edge-quads
    float acc[4][4] = {};
    for (int k = 0; k < D; ++k){
        float4 w = *(const float4*)&W1s[k*DH + jq*4];
        #pragma unroll
        for (int i = 0; i < 4; ++i){
            float f = Fs[(eq*4 + i)*132 + k];
            acc[i][0] += f * w.x;
            acc[i][1] += f * w.y;
            acc[i][2] += f * w.z;
            acc[i][3] += f * w.w;
        }
    }

    float4 b1v = *(const float4*)&b1[jq*4];
    float4 w2v = *(const float4*)&W2[jq*4];
    float part[4];
    #pragma unroll
    for (int i = 0; i < 4; ++i){
        float h0 = fmaxf(acc[i][0] + b1v.x, 0.f);
        float h1 = fmaxf(acc[i][1] + b1v.y, 0.f);
        float h2 = fmaxf(acc[i][2] + b1v.z, 0.f);
        float h3 = fmaxf(acc[i][3] + b1v.w, 0.f);
        part[i] = h0*w2v.x + h1*w2v.y + h2*w2v.z + h3*w2v.w;
    }
    #pragma unroll
    for (int off = 1; off < 16; off <<= 1){
        #pragma unroll
        for (int i = 0; i < 4; ++i) part[i] += __shfl_xor(part[i], off);
    }
    if (jq == 0){
        float b2v = b2[0];
        #pragma unroll
        for (int i = 0; i < 4; ++i){
            int el = eq*4 + i;
            float g = part[i] + b2v;
            gate[(size_t)tile*64 + el] = g;
            atomicMax(&gmaxkey[rxns[el]], fkey(g));
        }
    }
}

// Kernel 2: ex = exp(gate - gmax[rxn]); denom[rxn] += ex  (gate overwritten with ex)
__global__ __launch_bounds__(256) void exp_kernel(
    const int* __restrict__ he, float* __restrict__ gate,
    const unsigned* __restrict__ gmaxkey, float* __restrict__ denom,
    const int* __restrict__ flag)
{
    int e = blockIdx.x*256 + threadIdx.x;
    if (e >= NEDGE) return;
    int stride = (*flag) ? 2 : 1;
    int r = he[(size_t)(NEDGE + e) * stride];
    float m = fkey_inv(gmaxkey[r]);
    float ex = expf(gate[e] - m);
    gate[e] = ex;
    atomicAdd(&denom[r], ex);
}

// Kernel 3: t = relu(Wt^T f + bt); Z[rxn] += (ex/denom) * t   (atomic scatter)
// One block = 64 edges, 256 threads, register tile 4 edges x 8 cols (split j halves
// so each float4 LDS read pattern is only 2-way conflicted => free).
__global__ __launch_bounds__(256) void scatter_kernel(
    const float* __restrict__ feats, const int* __restrict__ he,
    const float* __restrict__ Wt, const float* __restrict__ bt,
    const float* __restrict__ ex, const float* __restrict__ denom,
    float* __restrict__ Z, const int* __restrict__ flag)
{
    __shared__ float Fs[64*132];
    __shared__ float Wts[D*D];     // [k][j]
    __shared__ int   mets[64];
    __shared__ int   rxns[64];
    __shared__ float als[64];

    const int tid  = threadIdx.x;
    const int tile = blockIdx.x;
    const int stride = (*flag) ? 2 : 1;

    if (tid < 64){
        int e = tile*64 + tid;
        mets[tid] = he[(size_t)e * stride];
        int r = he[(size_t)(NEDGE + e) * stride];
        rxns[tid] = r;
        als[tid]  = ex[e] / denom[r];
    }
    for (int i = tid; i < D*D/4; i += 256){
        ((float4*)Wts)[i] = ((const float4*)Wt)[i];
    }
    __syncthreads();

    {
        int er = tid >> 2;
        int c0 = tid & 3;
        const float4* src = (const float4*)(feats + (size_t)mets[er] * D);
        #pragma unroll
        for (int it = 0; it < 8; ++it){
            int c = c0 + 4*it;
            float4 v = src[c];
            *(float4*)&Fs[er*132 + c*4] = v;
        }
    }
    __syncthreads();

    const int jq = tid & 15;
    const int eq = tid >> 4;
    float acc[4][8] = {};
    for (int k = 0; k < D; ++k){
        float4 w0 = *(const float4*)&Wts[k*D + jq*4];
        float4 w1 = *(const float4*)&Wts[k*D + 64 + jq*4];
        #pragma unroll
        for (int i = 0; i < 4; ++i){
            float f = Fs[(eq*4 + i)*132 + k];
            acc[i][0] += f * w0.x;
            acc[i][1] += f * w0.y;
            acc[i][2] += f * w0.z;
            acc[i][3] += f * w0.w;
            acc[i][4] += f * w1.x;
            acc[i][5] += f * w1.y;
            acc[i][6] += f * w1.z;
            acc[i][7] += f * w1.w;
        }
    }

    float4 bt0 = *(const float4*)&bt[jq*4];
    float4 bt1 = *(const float4*)&bt[64 + jq*4];
    #pragma unroll
    for (int i = 0; i < 4; ++i){
        int el = eq*4 + i;
        int r  = rxns[el];
        float a = als[el];
        float* zrow = Z + (size_t)r * D;
        atomicAdd(&zrow[jq*4 + 0],      a * fmaxf(acc[i][0] + bt0.x, 0.f));
        atomicAdd(&zrow[jq*4 + 1],      a * fmaxf(acc[i][1] + bt0.y, 0.f));
        atomicAdd(&zrow[jq*4 + 2],      a * fmaxf(acc[i][2] + bt0.z, 0.f));
        atomicAdd(&zrow[jq*4 + 3],      a * fmaxf(acc[i][3] + bt0.w, 0.f));
        atomicAdd(&zrow[64 + jq*4 + 0], a * fmaxf(acc[i][4] + bt1.x, 0.f));
        atomicAdd(&zrow[64 + jq*4 + 1], a * fmaxf(acc[i][5] + bt1.y, 0.f));
        atomicAdd(&zrow[64 + jq*4 + 2], a * fmaxf(acc[i][6] + bt1.z, 0.f));
        atomicAdd(&zrow[64 + jq*4 + 3], a * fmaxf(acc[i][7] + bt1.w, 0.f));
    }
}

extern "C" void kernel_launch(void* const* d_in, const int* in_sizes, int n_in,
                              void* d_out, int out_size, void* d_ws, size_t ws_size,
                              hipStream_t stream)
{
    const float* feats = (const float*)d_in[0];
    const int*   he    = (const int*)d_in[1];
    const float* W1    = (const float*)d_in[2];
    const float* b1    = (const float*)d_in[3];
    const float* W2    = (const float*)d_in[4];
    const float* b2    = (const float*)d_in[5];
    const float* Wt    = (const float*)d_in[6];
    const float* bt    = (const float*)d_in[7];
    float* Z = (float*)d_out;

    char* ws = (char*)d_ws;
    float*    gate    = (float*)ws;                              // E floats
    unsigned* gmaxkey = (unsigned*)(ws + (size_t)NEDGE*4);       // N_RXN
    float*    denom   = (float*)(ws + (size_t)NEDGE*4 + (size_t)N_RXN*4);
    int*      flag    = (int*)(ws + (size_t)NEDGE*4 + (size_t)N_RXN*8);

    hipMemsetAsync(gmaxkey, 0, (size_t)N_RXN*4, stream);   // key 0 == below -inf
    hipMemsetAsync(denom,   0, (size_t)N_RXN*4, stream);
    hipMemsetAsync(d_out,   0, (size_t)out_size*4, stream);

    detect_kernel<<<1, 64, 0, stream>>>((const unsigned*)he, flag);
    gate_kernel<<<NEDGE/64, 256, 0, stream>>>(feats, he, W1, b1, W2, b2, gate, gmaxkey, flag);
    exp_kernel<<<(NEDGE + 255)/256, 256, 0, stream>>>(he, gate, gmaxkey, denom, flag);
    scatter_kernel<<<NEDGE/64, 256, 0, stream>>>(feats, he, Wt, bt, gate, denom, Z, flag);
}

// Round 2
// 1226.066 us; speedup vs baseline: 1.7831x; 1.7831x over previous
//
#include <hip/hip_runtime.h>
#include <hip/hip_bf16.h>
#include <math.h>

#define N_MET 20000
#define N_RXN 50000
#define NEDGE 1000000
#define D 128
#define DH 64

// Detect whether hyperedge_index is stored as int64 (little-endian: odd 32-bit
// words are high halves, all zero for indices < 2^31) or int32.
__global__ void detect_kernel(const unsigned* __restrict__ he, int* __restrict__ flag){
    if (threadIdx.x == 0){
        int is64 = 1;
        for (int i = 0; i < 64; ++i){
            if (he[2*i + 1] != 0u){ is64 = 0; break; }
        }
        *flag = is64;
    }
}

// Kernel 1: gate[e] = W2 . relu(W1^T f + b1) + b2 ; fused rxn histogram.
__global__ __launch_bounds__(256) void gate_kernel(
    const float* __restrict__ feats, const int* __restrict__ he,
    const float* __restrict__ W1, const float* __restrict__ b1,
    const float* __restrict__ W2, const float* __restrict__ b2,
    float* __restrict__ gate, int* __restrict__ count,
    const int* __restrict__ flag)
{
    __shared__ float Fs[64*132];     // padded stride 132 (bank rotation)
    __shared__ float W1s[D*DH];      // [k][j]
    __shared__ int   mets[64];

    const int tid  = threadIdx.x;
    const int tile = blockIdx.x;
    const int stride = (*flag) ? 2 : 1;

    if (tid < 64){
        int e = tile*64 + tid;
        mets[tid] = he[(size_t)e * stride];
        int r = he[(size_t)(NEDGE + e) * stride];
        atomicAdd(&count[r], 1);
    }
    for (int i = tid; i < D*DH/4; i += 256){
        ((float4*)W1s)[i] = ((const float4*)W1)[i];
    }
    __syncthreads();

    {
        int er = tid >> 2;
        int c0 = tid & 3;
        const float4* src = (const float4*)(feats + (size_t)mets[er] * D);
        #pragma unroll
        for (int it = 0; it < 8; ++it){
            int c = c0 + 4*it;
            float4 v = src[c];
            *(float4*)&Fs[er*132 + c*4] = v;
        }
    }
    __syncthreads();

    const int jq = tid & 15;
    const int eq = tid >> 4;
    float acc[4][4] = {};
    for (int k = 0; k < D; ++k){
        float4 w = *(const float4*)&W1s[k*DH + jq*4];
        #pragma unroll
        for (int i = 0; i < 4; ++i){
            float f = Fs[(eq*4 + i)*132 + k];
            acc[i][0] += f * w.x;
            acc[i][1] += f * w.y;
            acc[i][2] += f * w.z;
            acc[i][3] += f * w.w;
        }
    }

    float4 b1v = *(const float4*)&b1[jq*4];
    float4 w2v = *(const float4*)&W2[jq*4];
    float part[4];
    #pragma unroll
    for (int i = 0; i < 4; ++i){
        float h0 = fmaxf(acc[i][0] + b1v.x, 0.f);
        float h1 = fmaxf(acc[i][1] + b1v.y, 0.f);
        float h2 = fmaxf(acc[i][2] + b1v.z, 0.f);
        float h3 = fmaxf(acc[i][3] + b1v.w, 0.f);
        part[i] = h0*w2v.x + h1*w2v.y + h2*w2v.z + h3*w2v.w;
    }
    #pragma unroll
    for (int off = 1; off < 16; off <<= 1){
        #pragma unroll
        for (int i = 0; i < 4; ++i) part[i] += __shfl_xor(part[i], off);
    }
    if (jq == 0){
        float b2v = b2[0];
        #pragma unroll
        for (int i = 0; i < 4; ++i){
            gate[(size_t)tile*64 + eq*4 + i] = part[i] + b2v;
        }
    }
}

// Kernel 2: single-block exclusive scan over count[N_RXN] -> offsets, cursor.
__global__ __launch_bounds__(1024) void scan_kernel(
    const int* __restrict__ count, int* __restrict__ offsets, int* __restrict__ cursor)
{
    __shared__ int buf[1024];
    __shared__ int base;
    const int tid = threadIdx.x;
    if (tid == 0) base = 0;
    __syncthreads();
    for (int start = 0; start < N_RXN; start += 1024){
        int idx = start + tid;
        int v = (idx < N_RXN) ? count[idx] : 0;
        buf[tid] = v;
        __syncthreads();
        for (int off = 1; off < 1024; off <<= 1){
            int t = (tid >= off) ? buf[tid - off] : 0;
            __syncthreads();
            buf[tid] += t;
            __syncthreads();
        }
        int excl = buf[tid] - v;
        if (idx < N_RXN){
            offsets[idx] = base + excl;
            cursor[idx]  = base + excl;
        }
        __syncthreads();
        if (tid == 0) base += buf[1023];
        __syncthreads();
    }
    if (tid == 0) offsets[N_RXN] = base;
}

// Kernel 3: counting-sort reorder by reaction id.
__global__ __launch_bounds__(256) void reorder_kernel(
    const int* __restrict__ he, const float* __restrict__ gate,
    int* __restrict__ cursor, int* __restrict__ sorted_met,
    int* __restrict__ sorted_rxn, float* __restrict__ sorted_gate,
    const int* __restrict__ flag)
{
    int e = blockIdx.x*256 + threadIdx.x;
    if (e >= NEDGE) return;
    int stride = (*flag) ? 2 : 1;
    int m = he[(size_t)e * stride];
    int r = he[(size_t)(NEDGE + e) * stride];
    int pos = atomicAdd(&cursor[r], 1);
    sorted_met[pos]  = m;
    sorted_rxn[pos]  = r;
    sorted_gate[pos] = gate[e];
}

// Kernel 4: per-reaction softmax over its contiguous sorted range.
__global__ __launch_bounds__(256) void alpha_kernel(
    const int* __restrict__ offsets, const float* __restrict__ sorted_gate,
    float* __restrict__ sorted_alpha)
{
    int r = blockIdx.x*256 + threadIdx.x;
    if (r >= N_RXN) return;
    int s = offsets[r], e = offsets[r+1];
    if (s == e) return;
    float m = -INFINITY;
    for (int i = s; i < e; ++i) m = fmaxf(m, sorted_gate[i]);
    float sum = 0.f;
    for (int i = s; i < e; ++i) sum += expf(sorted_gate[i] - m);
    float inv = 1.0f / sum;
    for (int i = s; i < e; ++i) sorted_alpha[i] = expf(sorted_gate[i] - m) * inv;
}

// Kernel 5: t = relu(Wt^T f + bt); per-tile segmented reduce over sorted rxn,
// one atomicAdd per (run, column) instead of per (edge, column).
__global__ __launch_bounds__(256) void scatter_kernel(
    const float* __restrict__ feats, const int* __restrict__ sorted_met,
    const int* __restrict__ sorted_rxn, const float* __restrict__ sorted_alpha,
    const float* __restrict__ Wt, const float* __restrict__ bt,
    float* __restrict__ Z)
{
    __shared__ float Fs[64*132];   // F tile during GEMM, reused as alpha*t tile after
    __shared__ float Wts[D*D];     // [k][j]
    __shared__ int   mets[64];
    __shared__ int   rxns[64];
    __shared__ float als[64];

    const int tid  = threadIdx.x;
    const int tile = blockIdx.x;

    if (tid < 64){
        int p = tile*64 + tid;
        mets[tid] = sorted_met[p];
        rxns[tid] = sorted_rxn[p];
        als[tid]  = sorted_alpha[p];
    }
    for (int i = tid; i < D*D/4; i += 256){
        ((float4*)Wts)[i] = ((const float4*)Wt)[i];
    }
    __syncthreads();

    {
        int er = tid >> 2;
        int c0 = tid & 3;
        const float4* src = (const float4*)(feats + (size_t)mets[er] * D);
        #pragma unroll
        for (int it = 0; it < 8; ++it){
            int c = c0 + 4*it;
            float4 v = src[c];
            *(float4*)&Fs[er*132 + c*4] = v;
        }
    }
    __syncthreads();

    const int jq = tid & 15;
    const int eq = tid >> 4;
    float acc[4][8] = {};
    for (int k = 0; k < D; ++k){
        float4 w0 = *(const float4*)&Wts[k*D + jq*4];
        float4 w1 = *(const float4*)&Wts[k*D + 64 + jq*4];
        #pragma unroll
        for (int i = 0; i < 4; ++i){
            float f = Fs[(eq*4 + i)*132 + k];
            acc[i][0] += f * w0.x;
            acc[i][1] += f * w0.y;
            acc[i][2] += f * w0.z;
            acc[i][3] += f * w0.w;
            acc[i][4] += f * w1.x;
            acc[i][5] += f * w1.y;
            acc[i][6] += f * w1.z;
            acc[i][7] += f * w1.w;
        }
    }

    float4 bt0 = *(const float4*)&bt[jq*4];
    float4 bt1 = *(const float4*)&bt[64 + jq*4];

    __syncthreads();               // all F reads done; reuse Fs as alpha*t tile
    float* Ls = Fs;
    #pragma unroll
    for (int i = 0; i < 4; ++i){
        int e = eq*4 + i;
        float a = als[e];
        float4 o0, o1;
        o0.x = a * fmaxf(acc[i][0] + bt0.x, 0.f);
        o0.y = a * fmaxf(acc[i][1] + bt0.y, 0.f);
        o0.z = a * fmaxf(acc[i][2] + bt0.z, 0.f);
        o0.w = a * fmaxf(acc[i][3] + bt0.w, 0.f);
        o1.x = a * fmaxf(acc[i][4] + bt1.x, 0.f);
        o1.y = a * fmaxf(acc[i][5] + bt1.y, 0.f);
        o1.z = a * fmaxf(acc[i][6] + bt1.z, 0.f);
        o1.w = a * fmaxf(acc[i][7] + bt1.w, 0.f);
        *(float4*)&Ls[e*132 + jq*4]      = o0;
        *(float4*)&Ls[e*132 + 64 + jq*4] = o1;
    }
    __syncthreads();

    // Segmented reduce: 128 cols x 2 halves of 32 sorted edges each.
    const int col  = tid & 127;
    const int half = tid >> 7;
    const int e0 = half*32, e1 = e0 + 32;
    int   cur = rxns[e0];
    float s   = 0.f;
    for (int e = e0; e < e1; ++e){
        int r = rxns[e];
        if (r != cur){
            atomicAdd(&Z[(size_t)cur*D + col], s);
            s = 0.f;
            cur = r;
        }
        s += Ls[e*132 + col];
    }
    atomicAdd(&Z[(size_t)cur*D + col], s);
}

extern "C" void kernel_launch(void* const* d_in, const int* in_sizes, int n_in,
                              void* d_out, int out_size, void* d_ws, size_t ws_size,
                              hipStream_t stream)
{
    const float* feats = (const float*)d_in[0];
    const int*   he    = (const int*)d_in[1];
    const float* W1    = (const float*)d_in[2];
    const float* b1    = (const float*)d_in[3];
    const float* W2    = (const float*)d_in[4];
    const float* b2    = (const float*)d_in[5];
    const float* Wt    = (const float*)d_in[6];
    const float* bt    = (const float*)d_in[7];
    float* Z = (float*)d_out;

    char* ws = (char*)d_ws;
    size_t off = 0;
    float* gate         = (float*)(ws + off); off += (size_t)NEDGE*4;
    int*   count        = (int*)  (ws + off); off += (size_t)N_RXN*4;
    int*   offsets      = (int*)  (ws + off); off += (size_t)(N_RXN+1)*4;
    int*   cursor       = (int*)  (ws + off); off += (size_t)N_RXN*4;
    int*   sorted_met   = (int*)  (ws + off); off += (size_t)NEDGE*4;
    int*   sorted_rxn   = (int*)  (ws + off); off += (size_t)NEDGE*4;
    float* sorted_gate  = (float*)(ws + off); off += (size_t)NEDGE*4;
    float* sorted_alpha = (float*)(ws + off); off += (size_t)NEDGE*4;
    int*   flag         = (int*)  (ws + off); off += 64;

    hipMemsetAsync(count, 0, (size_t)N_RXN*4, stream);
    hipMemsetAsync(d_out, 0, (size_t)out_size*4, stream);

    detect_kernel<<<1, 64, 0, stream>>>((const unsigned*)he, flag);
    gate_kernel<<<NEDGE/64, 256, 0, stream>>>(feats, he, W1, b1, W2, b2, gate, count, flag);
    scan_kernel<<<1, 1024, 0, stream>>>(count, offsets, cursor);
    reorder_kernel<<<(NEDGE+255)/256, 256, 0, stream>>>(he, gate, cursor, sorted_met, sorted_rxn, sorted_gate, flag);
    alpha_kernel<<<(N_RXN+255)/256, 256, 0, stream>>>(offsets, sorted_gate, sorted_alpha);
    scatter_kernel<<<NEDGE/64, 256, 0, stream>>>(feats, sorted_met, sorted_rxn, sorted_alpha, Wt, bt, Z);
}

// Round 3
// 453.328 us; speedup vs baseline: 4.8224x; 2.7046x over previous
//
#include <hip/hip_runtime.h>
#include <hip/hip_bf16.h>
#include <math.h>

#define N_MET 20000
#define N_RXN 50000
#define NEDGE 1000000
#define D 128
#define DH 64

typedef __attribute__((ext_vector_type(8))) short short8;   // 8 bf16 raw bits
typedef __attribute__((ext_vector_type(4))) float f32x4;

__device__ __forceinline__ unsigned short f2bf(float x){
    __hip_bfloat16 b = __float2bfloat16(x);
    return *reinterpret_cast<unsigned short*>(&b);
}

// int64-vs-int32 layout detection for hyperedge_index
__global__ void detect_kernel(const unsigned* __restrict__ he, int* __restrict__ flag){
    if (threadIdx.x == 0){
        int is64 = 1;
        for (int i = 0; i < 64; ++i){
            if (he[2*i + 1] != 0u){ is64 = 0; break; }
        }
        *flag = is64;
    }
}

// feats fp32 -> bf16
__global__ __launch_bounds__(256) void cvt_feats_kernel(const float* __restrict__ in,
                                                        unsigned short* __restrict__ out){
    int i = blockIdx.x*256 + threadIdx.x;
    if (i < N_MET*D/4){
        float4 v = ((const float4*)in)[i];
        ushort4 o;
        o.x = f2bf(v.x); o.y = f2bf(v.y); o.z = f2bf(v.z); o.w = f2bf(v.w);
        ((ushort4*)out)[i] = o;
    }
}

// in[k*C + c] (KxC row-major) -> out[c*K + k] bf16 (transposed)
__global__ __launch_bounds__(256) void cvt_transpose_kernel(const float* __restrict__ in,
                                                            unsigned short* __restrict__ out,
                                                            int K, int C){
    int i = blockIdx.x*256 + threadIdx.x;
    if (i < K*C){
        int c = i / K, k = i - c*K;
        out[i] = f2bf(in[k*C + c]);
    }
}

// Kernel 1: gate via MFMA. 128-edge tile, 512 threads (8 waves), wave = 16 edges x 64 cols.
__global__ __launch_bounds__(512) void gate_kernel(
    const unsigned short* __restrict__ feats_bf, const int* __restrict__ he,
    const unsigned short* __restrict__ W1T_bf, const float* __restrict__ b1,
    const float* __restrict__ W2, const float* __restrict__ b2,
    float* __restrict__ gate, int* __restrict__ count,
    const int* __restrict__ flag)
{
    __shared__ __align__(16) unsigned short Fs[128*136];
    __shared__ __align__(16) unsigned short W1s[64*136];

    const int tid  = threadIdx.x;
    const long base = (long)blockIdx.x * 128;
    const int stride = (*flag) ? 2 : 1;

    if (tid < 128){
        long e = base + tid;
        if (e < NEDGE){
            int r = he[(size_t)(NEDGE + e) * stride];
            atomicAdd(&count[r], 1);
        }
    }
    // gather F tile (bf16): row = tid>>2, 4 threads/row, 4x16B each
    {
        int row = tid >> 2, q = tid & 3;
        long e = base + row;
        int m = (e < NEDGE) ? he[(size_t)e * stride] : 0;
        const unsigned short* src = feats_bf + (size_t)m * D;
        unsigned short* dst = &Fs[row*136];
        #pragma unroll
        for (int it = 0; it < 4; ++it){
            int k = q*8 + it*32;
            *(short8*)(dst + k) = *(const short8*)(src + k);
        }
    }
    // stage W1T [64][128] -> [64][136]
    for (int i = tid; i < 64*16; i += 512){
        int c = i >> 4, ch = i & 15;
        *(short8*)&W1s[c*136 + ch*8] = *(const short8*)&W1T_bf[c*128 + ch*8];
    }
    __syncthreads();

    const int lane = tid & 63;
    const int wave = tid >> 6;      // 0..7, owns edges wave*16..+16
    const int erow = lane & 15;
    const int kgrp = lane >> 4;     // 0..3

    f32x4 acc[4];
    #pragma unroll
    for (int cf = 0; cf < 4; ++cf) acc[cf] = (f32x4){0.f,0.f,0.f,0.f};

    #pragma unroll
    for (int ks = 0; ks < 4; ++ks){
        short8 a = *(const short8*)&Fs[(wave*16 + erow)*136 + ks*32 + kgrp*8];
        #pragma unroll
        for (int cf = 0; cf < 4; ++cf){
            short8 b = *(const short8*)&W1s[(cf*16 + erow)*136 + ks*32 + kgrp*8];
            acc[cf] = __builtin_amdgcn_mfma_f32_16x16x32_bf16(a, b, acc[cf], 0, 0, 0);
        }
    }

    // epilogue: gate[e] = sum_c relu(h+b1)*W2 + b2
    float p[4] = {0.f,0.f,0.f,0.f};
    #pragma unroll
    for (int cf = 0; cf < 4; ++cf){
        int c = cf*16 + erow;
        float b1c = b1[c], w2c = W2[c];
        #pragma unroll
        for (int r = 0; r < 4; ++r)
            p[r] += fmaxf(acc[cf][r] + b1c, 0.f) * w2c;
    }
    #pragma unroll
    for (int off = 1; off < 16; off <<= 1){
        #pragma unroll
        for (int r = 0; r < 4; ++r) p[r] += __shfl_xor(p[r], off);
    }
    if (erow == 0){
        float b2v = b2[0];
        #pragma unroll
        for (int r = 0; r < 4; ++r){
            long e = base + wave*16 + kgrp*4 + r;
            if (e < NEDGE) gate[e] = p[r] + b2v;
        }
    }
}

// Kernel 2: exclusive scan over count -> offsets, cursor (single block)
__global__ __launch_bounds__(1024) void scan_kernel(
    const int* __restrict__ count, int* __restrict__ offsets, int* __restrict__ cursor)
{
    __shared__ int buf[1024];
    __shared__ int base;
    const int tid = threadIdx.x;
    if (tid == 0) base = 0;
    __syncthreads();
    for (int start = 0; start < N_RXN; start += 1024){
        int idx = start + tid;
        int v = (idx < N_RXN) ? count[idx] : 0;
        buf[tid] = v;
        __syncthreads();
        for (int off = 1; off < 1024; off <<= 1){
            int t = (tid >= off) ? buf[tid - off] : 0;
            __syncthreads();
            buf[tid] += t;
            __syncthreads();
        }
        int excl = buf[tid] - v;
        if (idx < N_RXN){
            offsets[idx] = base + excl;
            cursor[idx]  = base + excl;
        }
        __syncthreads();
        if (tid == 0) base += buf[1023];
        __syncthreads();
    }
    if (tid == 0) offsets[N_RXN] = base;
}

// Kernel 3: counting-sort reorder; pack (rxn<<15)|met into one word.
__global__ __launch_bounds__(256) void reorder_kernel(
    const int* __restrict__ he, const float* __restrict__ gate,
    int* __restrict__ cursor, unsigned* __restrict__ sorted_pack,
    float* __restrict__ sorted_gate, const int* __restrict__ flag)
{
    int e = blockIdx.x*256 + threadIdx.x;
    if (e >= NEDGE) return;
    int stride = (*flag) ? 2 : 1;
    int m = he[(size_t)e * stride];
    int r = he[(size_t)(NEDGE + e) * stride];
    int pos = atomicAdd(&cursor[r], 1);
    sorted_pack[pos] = ((unsigned)r << 15) | (unsigned)m;
    sorted_gate[pos] = gate[e];
}

// Kernel 4: per-reaction softmax in place (gate -> alpha)
__global__ __launch_bounds__(256) void alpha_kernel(
    const int* __restrict__ offsets, float* __restrict__ g)
{
    int r = blockIdx.x*256 + threadIdx.x;
    if (r >= N_RXN) return;
    int s = offsets[r], e = offsets[r+1];
    if (s == e) return;
    float m = -INFINITY;
    for (int i = s; i < e; ++i) m = fmaxf(m, g[i]);
    float sum = 0.f;
    for (int i = s; i < e; ++i) sum += expf(g[i] - m);
    float inv = 1.0f / sum;
    for (int i = s; i < e; ++i) g[i] = expf(g[i] - m) * inv;
}

// Kernel 5: transform via MFMA + segmented reduce.
// 128-edge tile, 512 threads (8 waves), wave = 16 edges x 128 cols (32 MFMA).
__global__ __launch_bounds__(512) void scatter_kernel(
    const unsigned short* __restrict__ feats_bf, const unsigned* __restrict__ sorted_pack,
    const float* __restrict__ sorted_alpha, const unsigned short* __restrict__ WtT_bf,
    const float* __restrict__ bt, float* __restrict__ Z)
{
    __shared__ __align__(16) unsigned short Fs[128*136];
    __shared__ __align__(16) unsigned short Wts[128*136];   // reused as f32 staging [64][132]
    __shared__ int   rxns[128];
    __shared__ float als[128];

    const int tid  = threadIdx.x;
    const long base = (long)blockIdx.x * 128;

    if (tid < 128){
        long p = base + tid;
        unsigned pk = (p < NEDGE) ? sorted_pack[p] : 0u;
        rxns[tid] = (int)(pk >> 15);
        als[tid]  = (p < NEDGE) ? sorted_alpha[p] : 0.f;
    }
    // gather F tile
    {
        int row = tid >> 2, q = tid & 3;
        long p = base + row;
        int m = (p < NEDGE) ? (int)(sorted_pack[p] & 0x7FFFu) : 0;
        const unsigned short* src = feats_bf + (size_t)m * D;
        unsigned short* dst = &Fs[row*136];
        #pragma unroll
        for (int it = 0; it < 4; ++it){
            int k = q*8 + it*32;
            *(short8*)(dst + k) = *(const short8*)(src + k);
        }
    }
    // stage WtT [128][128] -> [128][136]
    for (int i = tid; i < 128*16; i += 512){
        int c = i >> 4, ch = i & 15;
        *(short8*)&Wts[c*136 + ch*8] = *(const short8*)&WtT_bf[c*128 + ch*8];
    }
    __syncthreads();

    const int lane = tid & 63;
    const int wave = tid >> 6;
    const int erow = lane & 15;
    const int kgrp = lane >> 4;

    f32x4 acc[8];
    #pragma unroll
    for (int cf = 0; cf < 8; ++cf) acc[cf] = (f32x4){0.f,0.f,0.f,0.f};

    #pragma unroll
    for (int ks = 0; ks < 4; ++ks){
        short8 a = *(const short8*)&Fs[(wave*16 + erow)*136 + ks*32 + kgrp*8];
        #pragma unroll
        for (int cf = 0; cf < 8; ++cf){
            short8 b = *(const short8*)&Wts[(cf*16 + erow)*136 + ks*32 + kgrp*8];
            acc[cf] = __builtin_amdgcn_mfma_f32_16x16x32_bf16(a, b, acc[cf], 0, 0, 0);
        }
    }
    __syncthreads();        // all Wts reads done; reuse as staging

    float* Ls = (float*)Wts;    // [64][132] f32 = 33792 B <= 34816 B
    #pragma unroll
    for (int h = 0; h < 2; ++h){
        if ((wave >> 2) == h){
            #pragma unroll
            for (int cf = 0; cf < 8; ++cf){
                int c = cf*16 + erow;
                float btc = bt[c];
                #pragma unroll
                for (int r = 0; r < 4; ++r){
                    int e = wave*16 + kgrp*4 + r;              // tile-local 0..127
                    float v = als[e] * fmaxf(acc[cf][r] + btc, 0.f);
                    Ls[(e - h*64)*132 + c] = v;
                }
            }
        }
        __syncthreads();
        // segmented reduce over this 64-edge half: 128 cols x 4 subsegments of 16
        {
            int col = tid & 127;
            int sg  = tid >> 7;
            int e0  = h*64 + sg*16;
            int cur = rxns[e0];
            float s = 0.f;
            #pragma unroll 4
            for (int i = 0; i < 16; ++i){
                int e = e0 + i;
                int r = rxns[e];
                if (r != cur){
                    atomicAdd(&Z[(size_t)cur*D + col], s);
                    s = 0.f; cur = r;
                }
                s += Ls[(sg*16 + i)*132 + col];
            }
            atomicAdd(&Z[(size_t)cur*D + col], s);
        }
        __syncthreads();
    }
}

extern "C" void kernel_launch(void* const* d_in, const int* in_sizes, int n_in,
                              void* d_out, int out_size, void* d_ws, size_t ws_size,
                              hipStream_t stream)
{
    const float* feats = (const float*)d_in[0];
    const int*   he    = (const int*)d_in[1];
    const float* W1    = (const float*)d_in[2];
    const float* b1    = (const float*)d_in[3];
    const float* W2    = (const float*)d_in[4];
    const float* b2    = (const float*)d_in[5];
    const float* Wt    = (const float*)d_in[6];
    const float* bt    = (const float*)d_in[7];
    float* Z = (float*)d_out;

    char* ws = (char*)d_ws;
    size_t off = 0;
    auto alloc = [&](size_t bytes)->char*{
        char* p = ws + off;
        off += (bytes + 255) & ~(size_t)255;
        return p;
    };
    unsigned short* feats_bf  = (unsigned short*)alloc((size_t)N_MET*D*2);
    unsigned short* WtT_bf    = (unsigned short*)alloc((size_t)D*D*2);
    unsigned short* W1T_bf    = (unsigned short*)alloc((size_t)D*DH*2);
    float*    gate        = (float*)   alloc((size_t)NEDGE*4);
    int*      count       = (int*)     alloc((size_t)N_RXN*4);
    int*      offsets     = (int*)     alloc((size_t)(N_RXN+1)*4);
    int*      cursor      = (int*)     alloc((size_t)N_RXN*4);
    unsigned* sorted_pack = (unsigned*)alloc((size_t)NEDGE*4);
    float*    sorted_ga   = (float*)   alloc((size_t)NEDGE*4);   // gate then alpha (in-place)
    int*      flag        = (int*)     alloc(64);

    hipMemsetAsync(count, 0, (size_t)N_RXN*4, stream);
    hipMemsetAsync(d_out, 0, (size_t)out_size*4, stream);

    detect_kernel<<<1, 64, 0, stream>>>((const unsigned*)he, flag);
    cvt_feats_kernel<<<(N_MET*D/4 + 255)/256, 256, 0, stream>>>(feats, feats_bf);
    cvt_transpose_kernel<<<(D*D + 255)/256, 256, 0, stream>>>(Wt, WtT_bf, D, D);
    cvt_transpose_kernel<<<(D*DH + 255)/256, 256, 0, stream>>>(W1, W1T_bf, D, DH);

    const int ntile = (NEDGE + 127)/128;
    gate_kernel<<<ntile, 512, 0, stream>>>(feats_bf, he, W1T_bf, b1, W2, b2, gate, count, flag);
    scan_kernel<<<1, 1024, 0, stream>>>(count, offsets, cursor);
    reorder_kernel<<<(NEDGE + 255)/256, 256, 0, stream>>>(he, gate, cursor, sorted_pack, sorted_ga, flag);
    alpha_kernel<<<(N_RXN + 255)/256, 256, 0, stream>>>(offsets, sorted_ga);
    scatter_kernel<<<ntile, 512, 0, stream>>>(feats_bf, sorted_pack, sorted_ga, WtT_bf, bt, Z);
}

// Round 5
// 432.335 us; speedup vs baseline: 5.0566x; 1.0486x over previous
//
#include <hip/hip_runtime.h>
#include <hip/hip_bf16.h>
#include <math.h>

#define N_MET 20000
#define N_RXN 50000
#define NEDGE 1000000
#define D 128
#define DH 64
#define NTILE ((NEDGE + 127) >> 7)   // 7813

typedef __attribute__((ext_vector_type(8))) short short8;   // 8 bf16 raw bits
typedef __attribute__((ext_vector_type(4))) float f32x4;

__device__ __forceinline__ unsigned short f2bf(float x){
    __hip_bfloat16 b = __float2bfloat16(x);
    return *reinterpret_cast<unsigned short*>(&b);
}
// monotone float<->uint key for atomicMax on floats (key 0 < any finite float's key)
__device__ __forceinline__ unsigned fkey(float x){
    unsigned u = __float_as_uint(x);
    return (u & 0x80000000u) ? ~u : (u | 0x80000000u);
}
__device__ __forceinline__ float fkey_inv(unsigned k){
    unsigned u = (k & 0x80000000u) ? (k ^ 0x80000000u) : ~k;
    return __uint_as_float(u);
}

// ---- fused converts + int64/int32 layout detect ----
#define NB_F ((N_MET*D/4 + 255)/256)   // 2500
#define NB_WT ((D*D + 255)/256)        // 64
#define NB_W1 ((D*DH + 255)/256)       // 32
__global__ __launch_bounds__(256) void cvt_all_kernel(
    const float* __restrict__ feats, const float* __restrict__ Wt,
    const float* __restrict__ W1, const unsigned* __restrict__ he,
    unsigned short* __restrict__ feats_bf, unsigned short* __restrict__ WtT_bf,
    unsigned short* __restrict__ W1T_bf, int* __restrict__ flag)
{
    int b = blockIdx.x;
    if (b < NB_F){
        int i = b*256 + threadIdx.x;
        if (i < N_MET*D/4){
            float4 v = ((const float4*)feats)[i];
            ushort4 o;
            o.x = f2bf(v.x); o.y = f2bf(v.y); o.z = f2bf(v.z); o.w = f2bf(v.w);
            ((ushort4*)feats_bf)[i] = o;
        }
    } else if (b < NB_F + NB_WT){
        int i = (b - NB_F)*256 + threadIdx.x;         // WtT[c*D + k] = Wt[k*D + c]
        if (i < D*D){ int c = i >> 7, k = i & 127; WtT_bf[i] = f2bf(Wt[k*D + c]); }
    } else if (b < NB_F + NB_WT + NB_W1){
        int i = (b - NB_F - NB_WT)*256 + threadIdx.x; // W1T[c*D + k] = W1[k*DH + c]
        if (i < DH*D){ int c = i >> 7, k = i & 127; W1T_bf[i] = f2bf(W1[k*DH + c]); }
    } else {
        if (threadIdx.x == 0){
            int is64 = 1;
            for (int i = 0; i < 64; ++i)
                if (he[2*i + 1] != 0u){ is64 = 0; break; }
            *flag = is64;
        }
    }
}

// ---- Kernel 1: gate via MFMA, persistent blocks, fused count-histogram + gmax atomicMax ----
__global__ __launch_bounds__(512) void gate_kernel(
    const unsigned short* __restrict__ feats_bf, const int* __restrict__ he,
    const unsigned short* __restrict__ W1T_bf, const float* __restrict__ b1,
    const float* __restrict__ W2, const float* __restrict__ b2,
    float* __restrict__ gate, int* __restrict__ count, unsigned* __restrict__ gmaxkey,
    const int* __restrict__ flag)
{
    __shared__ __align__(16) unsigned short Fs[128*136];
    __shared__ __align__(16) unsigned short W1s[64*136];
    __shared__ int rs[128];

    const int tid = threadIdx.x;
    const int stride = (*flag) ? 2 : 1;

    for (int i = tid; i < 64*16; i += 512){          // stage W1T once
        int c = i >> 4, ch = i & 15;
        *(short8*)&W1s[c*136 + ch*8] = *(const short8*)&W1T_bf[c*128 + ch*8];
    }

    const int lane = tid & 63;
    const int wave = tid >> 6;
    const int erow = lane & 15;
    const int kgrp = lane >> 4;

    float b1c[4], w2c[4];
    #pragma unroll
    for (int cf = 0; cf < 4; ++cf){
        int c = cf*16 + erow;
        b1c[cf] = b1[c]; w2c[cf] = W2[c];
    }
    const float b2v = b2[0];

    for (int tile = blockIdx.x; tile < NTILE; tile += gridDim.x){
        const long base = (long)tile * 128;
        if (tid < 128){
            long e = base + tid;
            int r = (e < NEDGE) ? he[(size_t)(NEDGE + e) * stride] : -1;
            rs[tid] = r;
            if (r >= 0) atomicAdd(&count[r], 1);
        }
        {   // gather F tile: 4 threads/row, 4x16B each
            int row = tid >> 2, q = tid & 3;
            long e = base + row;
            int m = (e < NEDGE) ? he[(size_t)e * stride] : 0;
            const unsigned short* src = feats_bf + (size_t)m * D;
            unsigned short* dst = &Fs[row*136];
            #pragma unroll
            for (int it = 0; it < 4; ++it){
                int k = q*8 + it*32;
                *(short8*)(dst + k) = *(const short8*)(src + k);
            }
        }
        __syncthreads();

        f32x4 acc[4];
        #pragma unroll
        for (int cf = 0; cf < 4; ++cf) acc[cf] = (f32x4){0.f,0.f,0.f,0.f};
        #pragma unroll
        for (int ks = 0; ks < 4; ++ks){
            short8 a = *(const short8*)&Fs[(wave*16 + erow)*136 + ks*32 + kgrp*8];
            #pragma unroll
            for (int cf = 0; cf < 4; ++cf){
                short8 b = *(const short8*)&W1s[(cf*16 + erow)*136 + ks*32 + kgrp*8];
                acc[cf] = __builtin_amdgcn_mfma_f32_16x16x32_bf16(a, b, acc[cf], 0, 0, 0);
            }
        }

        float p[4] = {0.f,0.f,0.f,0.f};
        #pragma unroll
        for (int cf = 0; cf < 4; ++cf){
            #pragma unroll
            for (int r = 0; r < 4; ++r)
                p[r] += fmaxf(acc[cf][r] + b1c[cf], 0.f) * w2c[cf];
        }
        #pragma unroll
        for (int off = 1; off < 16; off <<= 1){
            #pragma unroll
            for (int r = 0; r < 4; ++r) p[r] += __shfl_xor(p[r], off);
        }
        if (erow == 0){
            #pragma unroll
            for (int r = 0; r < 4; ++r){
                int el = wave*16 + kgrp*4 + r;
                long e = base + el;
                if (e < NEDGE){
                    float g = p[r] + b2v;
                    gate[e] = g;
                    atomicMax(&gmaxkey[rs[el]], fkey(g));
                }
            }
        }
        __syncthreads();    // protect rs/Fs before next iteration's writes
    }
}

// ---- Kernel 2: scan via wave shfl (3 barriers/chunk) -> offsets, cursor ----
__global__ __launch_bounds__(1024) void scan_kernel(
    const int* __restrict__ count, int* __restrict__ offsets, int* __restrict__ cursor)
{
    __shared__ int wsum[16];
    __shared__ int sbase;
    const int tid = threadIdx.x, lane = tid & 63, wid = tid >> 6;
    if (tid == 0) sbase = 0;
    __syncthreads();
    for (int start = 0; start < N_RXN; start += 1024){
        int idx = start + tid;
        int v = (idx < N_RXN) ? count[idx] : 0;
        int x = v;
        #pragma unroll
        for (int off = 1; off < 64; off <<= 1){
            int t = __shfl_up(x, off);
            if (lane >= off) x += t;
        }
        if (lane == 63) wsum[wid] = x;
        __syncthreads();
        if (wid == 0){
            int s = (lane < 16) ? wsum[lane] : 0;
            #pragma unroll
            for (int off = 1; off < 16; off <<= 1){
                int t = __shfl_up(s, off);
                if (lane >= off) s += t;
            }
            if (lane < 16) wsum[lane] = s;       // inclusive wave-sums
        }
        __syncthreads();
        int wbase = (wid == 0) ? 0 : wsum[wid-1];
        int excl = sbase + wbase + x - v;
        if (idx < N_RXN){ offsets[idx] = excl; cursor[idx] = excl; }
        __syncthreads();
        if (tid == 0) sbase += wsum[15];
        __syncthreads();
    }
    if (tid == 0) offsets[N_RXN] = sbase;
}

// ---- Kernel 3: counting-sort reorder, fused exp + denom atomic ----
__global__ __launch_bounds__(256) void reorder_kernel(
    const int* __restrict__ he, const float* __restrict__ gate,
    const unsigned* __restrict__ gmaxkey, int* __restrict__ cursor,
    uint2* __restrict__ sorted_pe, float* __restrict__ denom,
    const int* __restrict__ flag)
{
    int e = blockIdx.x*256 + threadIdx.x;
    if (e >= NEDGE) return;
    int stride = (*flag) ? 2 : 1;
    int m = he[(size_t)e * stride];
    int r = he[(size_t)(NEDGE + e) * stride];
    float ex = expf(gate[e] - fkey_inv(gmaxkey[r]));
    int pos = atomicAdd(&cursor[r], 1);
    uint2 pe; pe.x = ((unsigned)r << 15) | (unsigned)m; pe.y = __float_as_uint(ex);
    sorted_pe[pos] = pe;
    atomicAdd(&denom[r], ex);
}

// ---- Kernel 4: transform MFMA + segmented reduce, persistent blocks, Wt staged once ----
__global__ __launch_bounds__(512) void scatter_kernel(
    const unsigned short* __restrict__ feats_bf, const uint2* __restrict__ sorted_pe,
    const float* __restrict__ denom, const unsigned short* __restrict__ WtT_bf,
    const float* __restrict__ bt, float* __restrict__ Z)
{
    __shared__ __align__(16) unsigned short Fs[128*136];   // F tile, reused as f32 staging [64][132]
    __shared__ __align__(16) unsigned short Wts[128*136];
    __shared__ int   rxns[128];
    __shared__ float als[128];

    const int tid = threadIdx.x;
    for (int i = tid; i < 128*16; i += 512){         // stage WtT once
        int c = i >> 4, ch = i & 15;
        *(short8*)&Wts[c*136 + ch*8] = *(const short8*)&WtT_bf[c*128 + ch*8];
    }
    const int lane = tid & 63;
    const int wave = tid >> 6;
    const int erow = lane & 15;
    const int kgrp = lane >> 4;

    float btc[8];
    #pragma unroll
    for (int cf = 0; cf < 8; ++cf) btc[cf] = bt[cf*16 + erow];

    for (int tile = blockIdx.x; tile < NTILE; tile += gridDim.x){
        const long base = (long)tile * 128;
        if (tid < 128){
            long p = base + tid;
            if (p < NEDGE){
                uint2 pe = sorted_pe[p];
                int r = (int)(pe.x >> 15);
                rxns[tid] = r;
                als[tid]  = __uint_as_float(pe.y) / denom[r];
            } else { rxns[tid] = 0; als[tid] = 0.f; }
        }
        {   // gather F tile
            int row = tid >> 2, q = tid & 3;
            long p = base + row;
            int m = (p < NEDGE) ? (int)(sorted_pe[p].x & 0x7FFFu) : 0;
            const unsigned short* src = feats_bf + (size_t)m * D;
            unsigned short* dst = &Fs[row*136];
            #pragma unroll
            for (int it = 0; it < 4; ++it){
                int k = q*8 + it*32;
                *(short8*)(dst + k) = *(const short8*)(src + k);
            }
        }
        __syncthreads();

        f32x4 acc[8];
        #pragma unroll
        for (int cf = 0; cf < 8; ++cf) acc[cf] = (f32x4){0.f,0.f,0.f,0.f};
        #pragma unroll
        for (int ks = 0; ks < 4; ++ks){
            short8 a = *(const short8*)&Fs[(wave*16 + erow)*136 + ks*32 + kgrp*8];
            #pragma unroll
            for (int cf = 0; cf < 8; ++cf){
                short8 b = *(const short8*)&Wts[(cf*16 + erow)*136 + ks*32 + kgrp*8];
                acc[cf] = __builtin_amdgcn_mfma_f32_16x16x32_bf16(a, b, acc[cf], 0, 0, 0);
            }
        }
        __syncthreads();       // all Fs A-reads done; reuse Fs as f32 staging

        float* Ls = (float*)Fs;          // [64][132] f32 = 33792 B <= 34816 B
        #pragma unroll
        for (int h = 0; h < 2; ++h){
            if ((wave >> 2) == h){
                #pragma unroll
                for (int cf = 0; cf < 8; ++cf){
                    #pragma unroll
                    for (int r = 0; r < 4; ++r){
                        int el = (wave & 3)*16 + kgrp*4 + r;        // 0..63 within half
                        float v = als[h*64 + el] * fmaxf(acc[cf][r] + btc[cf], 0.f);
                        Ls[el*132 + cf*16 + erow] = v;
                    }
                }
            }
            __syncthreads();
            {   // segmented reduce: 128 cols x 4 subsegments of 16 edges
                int col = tid & 127;
                int sg  = tid >> 7;
                int e0  = h*64 + sg*16;
                int cur = rxns[e0];
                float s = 0.f;
                #pragma unroll 4
                for (int i = 0; i < 16; ++i){
                    int r = rxns[e0 + i];
                    if (r != cur){
                        atomicAdd(&Z[(size_t)cur*D + col], s);
                        s = 0.f; cur = r;
                    }
                    s += Ls[(sg*16 + i)*132 + col];
                }
                atomicAdd(&Z[(size_t)cur*D + col], s);
            }
            __syncthreads();   // staging/rxns/als stable before overwrite (h=1 / next tile)
        }
    }
}

extern "C" void kernel_launch(void* const* d_in, const int* in_sizes, int n_in,
                              void* d_out, int out_size, void* d_ws, size_t ws_size,
                              hipStream_t stream)
{
    const float* feats = (const float*)d_in[0];
    const int*   he    = (const int*)d_in[1];
    const float* W1    = (const float*)d_in[2];
    const float* b1    = (const float*)d_in[3];
    const float* W2    = (const float*)d_in[4];
    const float* b2    = (const float*)d_in[5];
    const float* Wt    = (const float*)d_in[6];
    const float* bt    = (const float*)d_in[7];
    float* Z = (float*)d_out;

    char* ws = (char*)d_ws;
    size_t off = 0;
    auto alloc = [&](size_t bytes)->char*{
        char* p = ws + off;
        off += (bytes + 255) & ~(size_t)255;
        return p;
    };
    unsigned short* feats_bf = (unsigned short*)alloc((size_t)N_MET*D*2);
    unsigned short* WtT_bf   = (unsigned short*)alloc((size_t)D*D*2);
    unsigned short* W1T_bf   = (unsigned short*)alloc((size_t)D*DH*2);
    float*    gate      = (float*)   alloc((size_t)NEDGE*4);
    char*     zero3     =            alloc((size_t)N_RXN*12);   // count | gmaxkey | denom
    int*      count     = (int*)      zero3;
    unsigned* gmaxkey   = (unsigned*)(zero3 + (size_t)N_RXN*4);
    float*    denom     = (float*)   (zero3 + (size_t)N_RXN*8);
    int*      offsets   = (int*)     alloc((size_t)(N_RXN+1)*4);
    int*      cursor    = (int*)     alloc((size_t)N_RXN*4);
    uint2*    sorted_pe = (uint2*)   alloc((size_t)NEDGE*8);
    int*      flag      = (int*)     alloc(64);

    hipMemsetAsync(zero3, 0, (size_t)N_RXN*12, stream);
    hipMemsetAsync(d_out, 0, (size_t)out_size*4, stream);

    cvt_all_kernel<<<NB_F + NB_WT + NB_W1 + 1, 256, 0, stream>>>(
        feats, Wt, W1, (const unsigned*)he, feats_bf, WtT_bf, W1T_bf, flag);
    gate_kernel<<<768, 512, 0, stream>>>(feats_bf, he, W1T_bf, b1, W2, b2,
                                         gate, count, gmaxkey, flag);
    scan_kernel<<<1, 1024, 0, stream>>>(count, offsets, cursor);
    reorder_kernel<<<(NEDGE + 255)/256, 256, 0, stream>>>(he, gate, gmaxkey, cursor,
                                                          sorted_pe, denom, flag);
    scatter_kernel<<<512, 512, 0, stream>>>(feats_bf, sorted_pe, denom, WtT_bf, bt, Z);
}